// Round 7
// baseline (939.108 us; speedup 1.0000x reference)
//
#include <hip/hip_runtime.h>

#define NEGV -1e9f
#define BB 32
#define CC 192
#define TXD 512
#define TYD 2048

// d_out layout (f32 elements)
#define E_DUR   0
#define E_ATTN  16384
#define E_MP    33570816
#define E_LS    46153728
#define E_TOTAL 58736640

// Scratch inside d_out (stream-ordered reuse):
//  l14  -> DUR region; L -> ATTN region; Zpl -> MP region; Bpl+dirs -> LS region
#define OFF_DIRS  6291456

// d_ws (bytes): tiny persistent scratch
#define WS_PATH 0ull
#define WS_YST  131072ull
#define WS_TXTY 196864ull
#define WS_NEED 262144ull

typedef _Float16 f16x8 __attribute__((ext_vector_type(8)));
typedef float f32x4 __attribute__((ext_vector_type(4)));

__device__ __forceinline__ void glds16(const void* g, void* l) {
    __builtin_amdgcn_global_load_lds((const __attribute__((address_space(1))) unsigned*)g,
                                     (__attribute__((address_space(3))) unsigned*)l, 16, 0, 0);
}
__device__ __forceinline__ unsigned packh(_Float16 a, _Float16 b) {
    union { _Float16 h[2]; unsigned u; } x; x.h[0] = a; x.h[1] = b; return x.u;
}

// ---------------- K0: B-side fp16 planes [b][4][t][c] + l14 + txty ----------------
__global__ __launch_bounds__(256) void k_prepB(const float* __restrict__ logs_p,
                                               const float* __restrict__ m_p,
                                               const int* __restrict__ xl,
                                               const int* __restrict__ yl,
                                               _Float16* __restrict__ Bpl,
                                               float* __restrict__ l14,
                                               unsigned* __restrict__ txty) {
    __shared__ float lst[CC][33];
    __shared__ float mst[CC][33];
    __shared__ float p14[8][32];
    int b = blockIdx.y, t0 = blockIdx.x * 32, tid = threadIdx.x;
    const float* lsb = logs_p + (size_t)b * CC * TXD + t0;
    const float* mb  = m_p    + (size_t)b * CC * TXD + t0;
#pragma unroll
    for (int i = 0; i < 24; ++i) {
        int u = i * 256 + tid, c = u >> 5, t = u & 31;
        lst[c][t] = lsb[(size_t)c * TXD + t];
        mst[c][t] = mb [(size_t)c * TXD + t];
    }
    __syncthreads();
    { int q = tid >> 5, t = tid & 31; float s = 0.f;
      for (int c = q * 24; c < q * 24 + 24; ++c) {
          float ls = lst[c][t], m = mst[c][t];
          float o = expf(-2.f * ls);
          s += -0.918938533204672741780329736406f - ls - 0.5f * m * m * o;
      }
      p14[q][t] = s; }
    __syncthreads();
    if (tid < 32) {
        float s = 0.f;
#pragma unroll
        for (int q = 0; q < 8; ++q) s += p14[q][tid];
        l14[b * TXD + t0 + tid] = s;
    }
    _Float16* Bb = Bpl + (size_t)b * (4 * TXD * CC);
    unsigned* B0 = (unsigned*)(Bb);
    unsigned* B1 = (unsigned*)(Bb + (size_t)1 * TXD * CC);
    unsigned* B2 = (unsigned*)(Bb + (size_t)2 * TXD * CC);
    unsigned* B3 = (unsigned*)(Bb + (size_t)3 * TXD * CC);
#pragma unroll
    for (int i = 0; i < 12; ++i) {
        int u = i * 256 + tid, t = u / 96, cp = u - t * 96, c = cp * 2;
        float ls0 = lst[c][t], ls1 = lst[c + 1][t];
        float m0 = mst[c][t], m1 = mst[c + 1][t];
        float o0 = expf(-2.f * ls0), o1 = expf(-2.f * ls1);
        float w0 = m0 * o0, w1 = m1 * o1;
        _Float16 oh0 = (_Float16)o0, oh1 = (_Float16)o1;
        _Float16 ol0 = (_Float16)(o0 - (float)oh0), ol1 = (_Float16)(o1 - (float)oh1);
        _Float16 wh0 = (_Float16)w0, wh1 = (_Float16)w1;
        _Float16 wl0 = (_Float16)(w0 - (float)wh0), wl1 = (_Float16)(w1 - (float)wh1);
        int ui = ((t0 + t) * CC + c) >> 1;
        B0[ui] = packh(oh0, oh1);
        B1[ui] = packh(ol0, ol1);
        B2[ui] = packh(wh0, wh1);
        B3[ui] = packh(wl0, wl1);
    }
    if (blockIdx.x == 0 && blockIdx.y == 0 && tid < BB) {
        int txv = min(max(xl[tid], 2), TXD);
        int tyv = min(max(yl[tid], 2), TYD);
        tyv = max(tyv, txv);
        txty[tid] = (unsigned)txv;
        txty[BB + tid] = (unsigned)tyv;
    }
}

// ---------------- K1: Z-side fp16 planes [b][4][sHalf][c] (one 1024-row half) ----------------
__global__ __launch_bounds__(256) void k_prepZ(const float* __restrict__ z_p,
                                               _Float16* __restrict__ Zpl, int sBase) {
    __shared__ float zt[CC][65];
    int b = blockIdx.y, s0 = blockIdx.x * 64, tid = threadIdx.x;
    const float* zb = z_p + (size_t)b * CC * TYD + sBase + s0;
#pragma unroll
    for (int i = 0; i < 48; ++i) {
        int u = i * 256 + tid, c = u >> 6, s = u & 63;
        zt[c][s] = zb[(size_t)c * TYD + s];
    }
    __syncthreads();
    _Float16* Zb = Zpl + (size_t)b * (4 * 1024 * CC);
    unsigned* Z0 = (unsigned*)(Zb);
    unsigned* Z1 = (unsigned*)(Zb + (size_t)1 * 1024 * CC);
    unsigned* Z2 = (unsigned*)(Zb + (size_t)2 * 1024 * CC);
    unsigned* Z3 = (unsigned*)(Zb + (size_t)3 * 1024 * CC);
#pragma unroll
    for (int i = 0; i < 24; ++i) {
        int u = i * 256 + tid, s = u / 96, cp = u - s * 96, c = cp * 2;
        float z0 = zt[c][s], z1 = zt[c + 1][s];
        float P0 = -0.5f * z0 * z0, P1 = -0.5f * z1 * z1;
        _Float16 ph0 = (_Float16)P0, ph1 = (_Float16)P1;
        _Float16 pl0 = (_Float16)(P0 - (float)ph0), pl1 = (_Float16)(P1 - (float)ph1);
        _Float16 zh0 = (_Float16)z0, zh1 = (_Float16)z1;
        _Float16 zl0 = (_Float16)(z0 - (float)zh0), zl1 = (_Float16)(z1 - (float)zh1);
        int ui = ((s0 + s) * CC + c) >> 1;
        Z0[ui] = packh(ph0, ph1);
        Z1[ui] = packh(pl0, pl1);
        Z2[ui] = packh(zh0, zh1);
        Z3[ui] = packh(zl0, zl1);
    }
}

// ---------------- K2: fp16x3 MFMA GEMM -> L (one 1024-row s-half) ----------------
__global__ __launch_bounds__(256, 2) void k_mm(const _Float16* __restrict__ Zpl,
                                               const _Float16* __restrict__ Bpl,
                                               const float* __restrict__ l14,
                                               const unsigned* __restrict__ txty,
                                               float* __restrict__ L, int sBase) {
    __shared__ __align__(16) char As[32768];  // [256][64] fp16, slot-swizzled
    __shared__ __align__(16) char Bs[16384];  // [128][64] fp16
    int bid = blockIdx.x;
    int xcd = bid & 7, idx = bid >> 3;
    int b = xcd + 8 * (idx >> 4);
    int tile = idx & 15;
    int s0 = (tile >> 2) * 256, t0 = (tile & 3) * 128;
    int txb = (int)txty[b], tyb = (int)txty[BB + b];
    int sg0 = sBase + s0;
    if (sg0 >= tyb) return;  // rows never read by DP; k_attn overwrites later
    int tid = threadIdx.x, l = tid & 63, w = tid >> 6;
    float* Lt = L + ((size_t)b * TYD + sg0) * TXD + t0;
    if (t0 >= txb) {  // fully col-masked: NEGV fill, no K-loop
#pragma unroll
        for (int i = 0; i < 32; ++i) {
            int u = i * 256 + tid, r = u >> 5, c4 = (u & 31) * 4;
            *(float4*)(Lt + (size_t)r * TXD + c4) = make_float4(NEGV, NEGV, NEGV, NEGV);
        }
        return;
    }
    f32x4 acc[4][8];
#pragma unroll
    for (int i = 0; i < 4; ++i)
#pragma unroll
        for (int j = 0; j < 8; ++j) acc[i][j] = (f32x4){0.f, 0.f, 0.f, 0.f};

    const char* Zb = (const char*)(Zpl + (size_t)b * (4 * 1024 * CC));
    const char* Bb = (const char*)(Bpl + (size_t)b * (4 * TXD * CC));
    int lrow = l >> 3;
    int gOff = lrow * 384 + (((l & 7) ^ lrow) * 16);
    int arow_off = (w * 64 + (l & 15)) * 128;
    int brow_off = (l & 15) * 128;
    int slot0 = (((l >> 4) + 0) ^ (l & 7)) * 16;
    int slot1 = (((l >> 4) + 4) ^ (l & 7)) * 16;

    for (int pass = 0; pass < 6; ++pass) {
        int ap = ((pass >= 3) ? 2 : 0) + ((pass == 2 || pass == 5) ? 1 : 0);
        int bp = ((pass >= 3) ? 2 : 0) + ((pass == 1 || pass == 4) ? 1 : 0);
        const char* Zp = Zb + ((size_t)ap * 1024 + s0) * 384;
        const char* Bp = Bb + ((size_t)bp * TXD + t0) * 384;
        for (int k0 = 0; k0 < 384; k0 += 128) {
            __syncthreads();
#pragma unroll
            for (int j = 0; j < 8; ++j) {
                int c = w * 8 + j;
                glds16(Zp + (size_t)c * (8 * 384) + gOff + k0, As + c * 1024);
            }
#pragma unroll
            for (int j = 0; j < 4; ++j) {
                int c = w * 4 + j;
                glds16(Bp + (size_t)c * (8 * 384) + gOff + k0, Bs + c * 1024);
            }
            __syncthreads();
#pragma unroll
            for (int ks = 0; ks < 2; ++ks) {
                int so = ks ? slot1 : slot0;
                f16x8 av[4], bv[8];
#pragma unroll
                for (int fm = 0; fm < 4; ++fm)
                    av[fm] = *(const f16x8*)(As + arow_off + fm * (16 * 128) + so);
#pragma unroll
                for (int fn = 0; fn < 8; ++fn)
                    bv[fn] = *(const f16x8*)(Bs + brow_off + fn * (16 * 128) + so);
#pragma unroll
                for (int fm = 0; fm < 4; ++fm)
#pragma unroll
                    for (int fn = 0; fn < 8; ++fn)
                        acc[fm][fn] = __builtin_amdgcn_mfma_f32_16x16x32_f16(
                            av[fm], bv[fn], acc[fm][fn], 0, 0, 0);
            }
        }
    }
    float l14v[8];
#pragma unroll
    for (int fn = 0; fn < 8; ++fn) l14v[fn] = l14[b * TXD + t0 + fn * 16 + (l & 15)];
    int sb = sg0 + w * 64 + (l >> 4) * 4;
    int tcol = t0 + (l & 15);
#pragma unroll
    for (int fm = 0; fm < 4; ++fm)
#pragma unroll
        for (int r = 0; r < 4; ++r) {
            int sg = sb + fm * 16 + r;
            bool sv = sg < tyb;
            float* Lrow = L + ((size_t)b * TYD + sg) * TXD;
#pragma unroll
            for (int fn = 0; fn < 8; ++fn) {
                int t = tcol + fn * 16;
                Lrow[t] = (sv && t < txb) ? (acc[fm][fn][r] + l14v[fn]) : NEGV;
            }
        }
}

// ---------------- K3: Viterbi DP, producer/consumer + pipelined shfl ----------------
// 2 waves as round 6. NEW: the per-row __shfl_up pair is issued one row EARLY
// (right after v[7]/p[7] of the current row are computed) and consumed at the
// NEXT row's i==0 column -> the ~120cy ds_bpermute latency hides under the
// i=6..0 select chain instead of sitting in the serial row chain.
// Chunk-reset subtlety: original shuffles post-reset p[7]; pipelined shuffle
// carries pre-reset value, so ppc is overridden with lane*8-1 (affine in lane).
__global__ __launch_bounds__(128) void k_dp(const float* __restrict__ L,
                                            const unsigned* __restrict__ txty,
                                            unsigned* __restrict__ dirsG,
                                            unsigned short* __restrict__ pathG,
                                            unsigned* __restrict__ ystartG,
                                            float* __restrict__ outDur) {
    __shared__ __align__(16) float ring[32 * 512];   // 64 KB
    __shared__ unsigned char dmaps[32 * 512];        // 16 KB
    __shared__ unsigned short path[TYD];             // 4 KB
    __shared__ unsigned cnt[513];
    __shared__ unsigned ebuf[32];
    int b = blockIdx.x, tid = threadIdx.x;
    int lane = tid & 63, wid = tid >> 6;
    int tx = (int)txty[b], ty = (int)txty[BB + b];
    const char* Lb = (const char*)(L + (size_t)b * (TYD * TXD));
    unsigned* dGw = dirsG + (size_t)b * (512 * 64);
    int G8 = (ty + 7) >> 3;

    if (wid == 1) {
        // ---------------- producer wave (unchanged from round 6) ----------------
        int c0s = lane ^ ((lane >> 3) & 7);
        int srcOff0 = c0s * 16;
        int srcOff1 = srcOff0 + 1024;
        char* ringc = (char*)ring;
#define STAGE_GRP(GR) do {                                                  \
        _Pragma("unroll")                                                   \
        for (int q_ = 0; q_ < 8; ++q_) {                                    \
            int r_ = 8 * (GR) + q_;                                         \
            int rc_ = min(r_, ty - 1);                                      \
            const char* src_ = Lb + (size_t)rc_ * 2048;                     \
            char* dst_ = ringc + (size_t)(r_ & 31) * 2048;                  \
            glds16(src_ + srcOff0, dst_);                                   \
            glds16(src_ + srcOff1, dst_ + 1024);                            \
        } } while (0)
        STAGE_GRP(0); STAGE_GRP(1); STAGE_GRP(2);          // 48 outstanding
        asm volatile("s_waitcnt vmcnt(16)" ::: "memory");  // groups 0,1 landed
        __builtin_amdgcn_s_barrier();                      // barrier #0
        for (int g = 0; g < G8; ++g) {
            __builtin_amdgcn_sched_barrier(0);
            STAGE_GRP(g + 3);                              // 32 outstanding
            asm volatile("s_waitcnt vmcnt(16)" ::: "memory"); // group g+2 landed
            __builtin_amdgcn_s_barrier();                  // barrier #(g+1)
        }
#undef STAGE_GRP
    } else {
        // ---------------- consumer wave (DP) ----------------
        int sl0 = (2 * lane) ^ ((lane >> 2) & 7);
        int sl1 = sl0 ^ 1;
        const char* ringc = (const char*)ring;
        float v[8];
        unsigned p[8];
        float vpc = NEGV;      // shfl result pipelined from previous row
        unsigned ppc = 0u;
        float4 loA[8], hiA[8], loB[8], hiB[8];
#define READ_GRP(LO, HI, GN) do {                                           \
        const char* rb_ = ringc + (((GN) & 3) << 14);                       \
        _Pragma("unroll")                                                   \
        for (int q_ = 0; q_ < 8; ++q_) {                                    \
            LO[q_] = *(const float4*)(rb_ + q_ * 2048 + sl0 * 16);          \
            HI[q_] = *(const float4*)(rb_ + q_ * 2048 + sl1 * 16);          \
        } } while (0)
#define DP_GRP(LO, HI, G_) do {                                             \
        unsigned w0_ = 0, w1_ = 0;                                          \
        _Pragma("unroll")                                                   \
        for (int q_ = 0; q_ < 8; ++q_) {                                    \
            int y_ = 8 * (G_) + q_;                                         \
            if (y_ < ty) {                                                  \
                float cur_[8] = {LO[q_].x, LO[q_].y, LO[q_].z, LO[q_].w,    \
                                 HI[q_].x, HI[q_].y, HI[q_].z, HI[q_].w};   \
                unsigned bits_ = 0u;                                        \
                float v7n_; unsigned p7n_;                                  \
                if ((G_) == 0 && q_ == 0) {                                 \
                    _Pragma("unroll")                                       \
                    for (int i = 0; i < 8; ++i) {                           \
                        int x_ = lane * 8 + i;                              \
                        v[i] = (x_ == 0) ? cur_[i] : NEGV;                  \
                        p[i] = (unsigned)x_;                                \
                    }                                                       \
                    v7n_ = v[7]; p7n_ = p[7];                               \
                } else {                                                    \
                    bool d7_ = v[6] > v[7];                                 \
                    v7n_ = cur_[7] + (d7_ ? v[6] : v[7]);                   \
                    p7n_ = d7_ ? p[6] : p[7];                               \
                    bits_ = d7_ ? 0x80u : 0u;                               \
                }                                                           \
                float vsh_ = __shfl_up(v7n_, 1);   /* issued EARLY */       \
                unsigned psh_ = (unsigned)__shfl_up((int)p7n_, 1);          \
                if (!((G_) == 0 && q_ == 0)) {                              \
                    _Pragma("unroll")                                       \
                    for (int i = 6; i >= 1; --i) {                          \
                        bool di_ = v[i - 1] > v[i];                         \
                        v[i] = cur_[i] + (di_ ? v[i - 1] : v[i]);           \
                        p[i] = di_ ? p[i - 1] : p[i];                       \
                        bits_ |= (di_ ? 1u : 0u) << i;                      \
                    }                                                       \
                    bool d0_ = vpc > v[0];   /* uses PREVIOUS row's shfl */ \
                    v[0] = cur_[0] + (d0_ ? vpc : v[0]);                    \
                    p[0] = d0_ ? ppc : p[0];                                \
                    bits_ |= d0_ ? 1u : 0u;                                 \
                    v[7] = v7n_; p[7] = p7n_;                               \
                }                                                           \
                vpc = (lane == 0) ? NEGV : vsh_;                            \
                ppc = psh_;                                                 \
                if (q_ < 4) w0_ |= bits_ << (8 * q_);                       \
                else        w1_ |= bits_ << (8 * (q_ - 4));                 \
                if (q_ == 0 && ((G_) & 7) == 0 && (G_) != 0) {              \
                    _Pragma("unroll")                                       \
                    for (int i = 0; i < 8; ++i) p[i] = (unsigned)(lane * 8 + i); \
                    ppc = (unsigned)(lane * 8 - 1);  /* post-reset shfl value */ \
                }                                                           \
                if (q_ == 7 && ((G_) & 7) == 7) {                           \
                    int c_ = y_ >> 6;                                       \
                    _Pragma("unroll")                                       \
                    for (int i = 0; i < 8; ++i)                             \
                        dmaps[c_ * 512 + lane * 8 + i] =                    \
                            (unsigned char)((unsigned)(lane * 8 + i) - p[i]); \
                }                                                           \
            }                                                               \
        }                                                                   \
        dGw[(2 * (G_)) * 64 + lane] = w0_;                                  \
        dGw[(2 * (G_) + 1) * 64 + lane] = w1_;                              \
        } while (0)
        __builtin_amdgcn_s_barrier();                  // barrier #0
        __builtin_amdgcn_sched_barrier(0);
        READ_GRP(loA, hiA, 0);
        for (int g = 0; g < G8;) {
            READ_GRP(loB, hiB, g + 1);   // landed by barrier #g; hides under DP below
            DP_GRP(loA, hiA, g);
            ++g;
            __builtin_amdgcn_s_barrier();              // barrier #g
            __builtin_amdgcn_sched_barrier(0);
            if (g >= G8) break;
            READ_GRP(loA, hiA, g + 1);
            DP_GRP(loB, hiB, g);
            ++g;
            __builtin_amdgcn_s_barrier();              // barrier #g
            __builtin_amdgcn_sched_barrier(0);
        }
#undef READ_GRP
#undef DP_GRP
    }
    asm volatile("s_waitcnt vmcnt(0)" ::: "memory");  // consumer: dirs stores visible
    __syncthreads();

    int c0 = (ty - 1) >> 6;
    if (tid == 0) {
        int pos = tx - 1;
        for (int y = ty - 1; y >= (c0 << 6); --y) {  // top partial chunk
            path[y] = (unsigned short)pos;
            unsigned wv = dGw[(y >> 2) * 64 + (pos >> 3)];
            pos -= (int)((wv >> (((y & 3) << 3) | (pos & 7))) & 1u);
        }
        for (int c = c0 - 1; c >= 0; --c) {  // chunk-boundary resolution via dmaps
            ebuf[c] = (unsigned)pos;
            int P = pos - (int)dmaps[c * 512 + pos];
            unsigned wv = dGw[(c << 4) * 64 + (P >> 3)];  // row c*64 -> dword group c*16
            pos = P - (int)((wv >> (P & 7)) & 1u);
        }
    }
    __syncthreads();
    if (tid < c0) {  // parallel per-chunk chases (c0 <= 31 -> wave 0)
        int c = tid;
        int pos = (int)ebuf[c];
        for (int y = (c << 6) + 63; y >= (c << 6); --y) {
            path[y] = (unsigned short)pos;
            unsigned wv = dGw[(y >> 2) * 64 + (pos >> 3)];
            pos -= (int)((wv >> (((y & 3) << 3) | (pos & 7))) & 1u);
        }
    }
    __syncthreads();

    for (int i = tid; i < 513; i += 128) cnt[i] = 0;
    __syncthreads();
    for (int y = tid; y < ty; y += 128) atomicAdd(&cnt[path[y]], 1u);
    __syncthreads();

    if (wid == 0) {
        unsigned c8[8], lsum = 0;
#pragma unroll
        for (int i = 0; i < 8; ++i) {
            c8[i] = cnt[lane * 8 + i];
            lsum += c8[i];
        }
        unsigned incl = lsum;
        for (int d = 1; d < 64; d <<= 1) {
            unsigned t = (unsigned)__shfl_up((int)incl, d);
            if (lane >= d) incl += t;
        }
        unsigned run = incl - lsum;
#pragma unroll
        for (int i = 0; i < 8; ++i) {
            int x = lane * 8 + i;
            ystartG[b * 513 + x] = run;
            outDur[(size_t)b * TXD + x] = (float)c8[i];
            run += c8[i];
        }
        if (lane == 0) ystartG[b * 513 + 512] = (unsigned)ty;
    }
    for (int y = tid; y < ty; y += 128) pathG[b * TYD + y] = path[y];
}

// ---------------- K4: dense attn rows (f32 0/1) ----------------
__global__ __launch_bounds__(64) void k_attn(const unsigned* __restrict__ ystartG,
                                             float* __restrict__ out) {
    int x = blockIdx.x, b = blockIdx.y, lane = threadIdx.x;
    unsigned s0 = ystartG[b * 513 + x];
    unsigned s1 = ystartG[b * 513 + x + 1];
    float* row = out + E_ATTN + ((size_t)(b * TXD + x)) * TYD + lane * 32;
#pragma unroll
    for (int k = 0; k < 8; ++k) {
        unsigned y0 = (unsigned)(lane * 32 + k * 4);
        float4 o;
        o.x = (y0 + 0 >= s0 && y0 + 0 < s1) ? 1.0f : 0.0f;
        o.y = (y0 + 1 >= s0 && y0 + 1 < s1) ? 1.0f : 0.0f;
        o.z = (y0 + 2 >= s0 && y0 + 2 < s1) ? 1.0f : 0.0f;
        o.w = (y0 + 3 >= s0 && y0 + 3 < s1) ? 1.0f : 0.0f;
        *(float4*)(row + k * 4) = o;
    }
}

// ---------------- K5: m_p_dur / logs_p_dur gathers (f32) ----------------
__global__ __launch_bounds__(256) void k_gather(const float* __restrict__ m_p,
                                                const float* __restrict__ logs_p,
                                                const unsigned short* __restrict__ pathG,
                                                const unsigned* __restrict__ txty,
                                                float* __restrict__ out) {
    __shared__ unsigned short px[64];
    int yc = blockIdx.x, b = blockIdx.y;
    int y0 = yc * 64, tid = threadIdx.x;
    int lane = tid & 63, w = tid >> 6;
    int ty = (int)txty[BB + b];
    if (tid < 64) px[tid] = (y0 + tid < ty) ? pathG[b * TYD + y0 + tid] : 0;
    __syncthreads();
    bool act = (y0 + lane) < ty;
    int xx = (int)px[lane];
    for (int c = w; c < CC; c += 4) {
        float mv = act ? m_p[((size_t)b * CC + c) * TXD + xx] : 0.0f;
        float lv = act ? logs_p[((size_t)b * CC + c) * TXD + xx] : 0.0f;
        size_t oidx = ((size_t)(b * CC + c)) * TYD + y0 + lane;
        out[E_MP + oidx] = mv;
        out[E_LS + oidx] = lv;
    }
}

extern "C" void kernel_launch(void* const* d_in, const int* in_sizes, int n_in,
                              void* d_out, int out_size, void* d_ws, size_t ws_size,
                              hipStream_t stream) {
    if (out_size < E_TOTAL) return;
    if (ws_size < WS_NEED) return;
    const float* z_p    = (const float*)d_in[0];
    const float* m_p    = (const float*)d_in[1];
    const float* logs_p = (const float*)d_in[2];
    const int* xl       = (const int*)d_in[3];
    const int* yl       = (const int*)d_in[4];
    float* out = (float*)d_out;
    char* ws = (char*)d_ws;

    float* l14            = out + E_DUR;
    float* L              = out + E_ATTN;
    _Float16* Zpl         = (_Float16*)(out + E_MP);
    _Float16* Bpl         = (_Float16*)(out + E_LS);
    unsigned* dirsG       = (unsigned*)(out + E_LS + OFF_DIRS);
    unsigned short* pathG = (unsigned short*)(ws + WS_PATH);
    unsigned* ystartG     = (unsigned*)(ws + WS_YST);
    unsigned* txty        = (unsigned*)(ws + WS_TXTY);

    hipLaunchKernelGGL(k_prepB, dim3(16, BB), dim3(256), 0, stream,
                       logs_p, m_p, xl, yl, Bpl, l14, txty);
    hipLaunchKernelGGL(k_prepZ, dim3(16, BB), dim3(256), 0, stream, z_p, Zpl, 0);
    hipLaunchKernelGGL(k_mm, dim3(512), dim3(256), 0, stream, Zpl, Bpl, l14, txty, L, 0);
    hipLaunchKernelGGL(k_prepZ, dim3(16, BB), dim3(256), 0, stream, z_p, Zpl, 1024);
    hipLaunchKernelGGL(k_mm, dim3(512), dim3(256), 0, stream, Zpl, Bpl, l14, txty, L, 1024);
    hipLaunchKernelGGL(k_dp, dim3(BB), dim3(128), 0, stream, L, txty, dirsG, pathG, ystartG, out + E_DUR);
    hipLaunchKernelGGL(k_attn, dim3(TXD, BB), dim3(64), 0, stream, ystartG, out);
    hipLaunchKernelGGL(k_gather, dim3(TYD / 64, BB), dim3(256), 0, stream, m_p, logs_p, pathG, txty, out);
}

// Round 8
// 523.934 us; speedup vs baseline: 1.7924x; 1.7924x over previous
//
#include <hip/hip_runtime.h>

#define NEGV -1e9f
#define BB 32
#define CC 192
#define TXD 512
#define TYD 2048

// d_out layout (f32 elements)
#define E_DUR   0
#define E_ATTN  16384
#define E_MP    33570816
#define E_LS    46153728
#define E_TOTAL 58736640

// Scratch inside d_out (stream-ordered reuse):
//  l14  -> DUR region; L -> ATTN region; Zpl -> MP region; Bpl+dirs -> LS region
#define OFF_DIRS  6291456

// d_ws (bytes): tiny persistent scratch
#define WS_PATH 0ull
#define WS_YST  131072ull
#define WS_TXTY 196864ull
#define WS_NEED 262144ull

typedef _Float16 f16x8 __attribute__((ext_vector_type(8)));
typedef float f32x4 __attribute__((ext_vector_type(4)));

__device__ __forceinline__ void glds16(const void* g, void* l) {
    __builtin_amdgcn_global_load_lds((const __attribute__((address_space(1))) unsigned*)g,
                                     (__attribute__((address_space(3))) unsigned*)l, 16, 0, 0);
}
__device__ __forceinline__ unsigned packh(_Float16 a, _Float16 b) {
    union { _Float16 h[2]; unsigned u; } x; x.h[0] = a; x.h[1] = b; return x.u;
}

// ---------------- K0: B-side fp16 planes [b][4][t][c] + l14 + txty ----------------
__global__ __launch_bounds__(256) void k_prepB(const float* __restrict__ logs_p,
                                               const float* __restrict__ m_p,
                                               const int* __restrict__ xl,
                                               const int* __restrict__ yl,
                                               _Float16* __restrict__ Bpl,
                                               float* __restrict__ l14,
                                               unsigned* __restrict__ txty) {
    __shared__ float lst[CC][33];
    __shared__ float mst[CC][33];
    __shared__ float p14[8][32];
    int b = blockIdx.y, t0 = blockIdx.x * 32, tid = threadIdx.x;
    const float* lsb = logs_p + (size_t)b * CC * TXD + t0;
    const float* mb  = m_p    + (size_t)b * CC * TXD + t0;
#pragma unroll
    for (int i = 0; i < 24; ++i) {
        int u = i * 256 + tid, c = u >> 5, t = u & 31;
        lst[c][t] = lsb[(size_t)c * TXD + t];
        mst[c][t] = mb [(size_t)c * TXD + t];
    }
    __syncthreads();
    { int q = tid >> 5, t = tid & 31; float s = 0.f;
      for (int c = q * 24; c < q * 24 + 24; ++c) {
          float ls = lst[c][t], m = mst[c][t];
          float o = expf(-2.f * ls);
          s += -0.918938533204672741780329736406f - ls - 0.5f * m * m * o;
      }
      p14[q][t] = s; }
    __syncthreads();
    if (tid < 32) {
        float s = 0.f;
#pragma unroll
        for (int q = 0; q < 8; ++q) s += p14[q][tid];
        l14[b * TXD + t0 + tid] = s;
    }
    _Float16* Bb = Bpl + (size_t)b * (4 * TXD * CC);
    unsigned* B0 = (unsigned*)(Bb);
    unsigned* B1 = (unsigned*)(Bb + (size_t)1 * TXD * CC);
    unsigned* B2 = (unsigned*)(Bb + (size_t)2 * TXD * CC);
    unsigned* B3 = (unsigned*)(Bb + (size_t)3 * TXD * CC);
#pragma unroll
    for (int i = 0; i < 12; ++i) {
        int u = i * 256 + tid, t = u / 96, cp = u - t * 96, c = cp * 2;
        float ls0 = lst[c][t], ls1 = lst[c + 1][t];
        float m0 = mst[c][t], m1 = mst[c + 1][t];
        float o0 = expf(-2.f * ls0), o1 = expf(-2.f * ls1);
        float w0 = m0 * o0, w1 = m1 * o1;
        _Float16 oh0 = (_Float16)o0, oh1 = (_Float16)o1;
        _Float16 ol0 = (_Float16)(o0 - (float)oh0), ol1 = (_Float16)(o1 - (float)oh1);
        _Float16 wh0 = (_Float16)w0, wh1 = (_Float16)w1;
        _Float16 wl0 = (_Float16)(w0 - (float)wh0), wl1 = (_Float16)(w1 - (float)wh1);
        int ui = ((t0 + t) * CC + c) >> 1;
        B0[ui] = packh(oh0, oh1);
        B1[ui] = packh(ol0, ol1);
        B2[ui] = packh(wh0, wh1);
        B3[ui] = packh(wl0, wl1);
    }
    if (blockIdx.x == 0 && blockIdx.y == 0 && tid < BB) {
        int txv = min(max(xl[tid], 2), TXD);
        int tyv = min(max(yl[tid], 2), TYD);
        tyv = max(tyv, txv);
        txty[tid] = (unsigned)txv;
        txty[BB + tid] = (unsigned)tyv;
    }
}

// ---------------- K1: Z-side fp16 planes [b][4][sHalf][c] (one 1024-row half) ----------------
__global__ __launch_bounds__(256) void k_prepZ(const float* __restrict__ z_p,
                                               _Float16* __restrict__ Zpl, int sBase) {
    __shared__ float zt[CC][65];
    int b = blockIdx.y, s0 = blockIdx.x * 64, tid = threadIdx.x;
    const float* zb = z_p + (size_t)b * CC * TYD + sBase + s0;
#pragma unroll
    for (int i = 0; i < 48; ++i) {
        int u = i * 256 + tid, c = u >> 6, s = u & 63;
        zt[c][s] = zb[(size_t)c * TYD + s];
    }
    __syncthreads();
    _Float16* Zb = Zpl + (size_t)b * (4 * 1024 * CC);
    unsigned* Z0 = (unsigned*)(Zb);
    unsigned* Z1 = (unsigned*)(Zb + (size_t)1 * 1024 * CC);
    unsigned* Z2 = (unsigned*)(Zb + (size_t)2 * 1024 * CC);
    unsigned* Z3 = (unsigned*)(Zb + (size_t)3 * 1024 * CC);
#pragma unroll
    for (int i = 0; i < 24; ++i) {
        int u = i * 256 + tid, s = u / 96, cp = u - s * 96, c = cp * 2;
        float z0 = zt[c][s], z1 = zt[c + 1][s];
        float P0 = -0.5f * z0 * z0, P1 = -0.5f * z1 * z1;
        _Float16 ph0 = (_Float16)P0, ph1 = (_Float16)P1;
        _Float16 pl0 = (_Float16)(P0 - (float)ph0), pl1 = (_Float16)(P1 - (float)ph1);
        _Float16 zh0 = (_Float16)z0, zh1 = (_Float16)z1;
        _Float16 zl0 = (_Float16)(z0 - (float)zh0), zl1 = (_Float16)(z1 - (float)zh1);
        int ui = ((s0 + s) * CC + c) >> 1;
        Z0[ui] = packh(ph0, ph1);
        Z1[ui] = packh(pl0, pl1);
        Z2[ui] = packh(zh0, zh1);
        Z3[ui] = packh(zl0, zl1);
    }
}

// ---------------- K2: fp16x3 MFMA GEMM -> L (one 1024-row s-half) ----------------
__global__ __launch_bounds__(256, 2) void k_mm(const _Float16* __restrict__ Zpl,
                                               const _Float16* __restrict__ Bpl,
                                               const float* __restrict__ l14,
                                               const unsigned* __restrict__ txty,
                                               float* __restrict__ L, int sBase) {
    __shared__ __align__(16) char As[32768];  // [256][64] fp16, slot-swizzled
    __shared__ __align__(16) char Bs[16384];  // [128][64] fp16
    int bid = blockIdx.x;
    int xcd = bid & 7, idx = bid >> 3;
    int b = xcd + 8 * (idx >> 4);
    int tile = idx & 15;
    int s0 = (tile >> 2) * 256, t0 = (tile & 3) * 128;
    int txb = (int)txty[b], tyb = (int)txty[BB + b];
    int sg0 = sBase + s0;
    if (sg0 >= tyb) return;  // rows never read by DP; k_attn overwrites later
    int tid = threadIdx.x, l = tid & 63, w = tid >> 6;
    float* Lt = L + ((size_t)b * TYD + sg0) * TXD + t0;
    if (t0 >= txb) {  // fully col-masked: NEGV fill, no K-loop
#pragma unroll
        for (int i = 0; i < 32; ++i) {
            int u = i * 256 + tid, r = u >> 5, c4 = (u & 31) * 4;
            *(float4*)(Lt + (size_t)r * TXD + c4) = make_float4(NEGV, NEGV, NEGV, NEGV);
        }
        return;
    }
    f32x4 acc[4][8];
#pragma unroll
    for (int i = 0; i < 4; ++i)
#pragma unroll
        for (int j = 0; j < 8; ++j) acc[i][j] = (f32x4){0.f, 0.f, 0.f, 0.f};

    const char* Zb = (const char*)(Zpl + (size_t)b * (4 * 1024 * CC));
    const char* Bb = (const char*)(Bpl + (size_t)b * (4 * TXD * CC));
    int lrow = l >> 3;
    int gOff = lrow * 384 + (((l & 7) ^ lrow) * 16);
    int arow_off = (w * 64 + (l & 15)) * 128;
    int brow_off = (l & 15) * 128;
    int slot0 = (((l >> 4) + 0) ^ (l & 7)) * 16;
    int slot1 = (((l >> 4) + 4) ^ (l & 7)) * 16;

    for (int pass = 0; pass < 6; ++pass) {
        int ap = ((pass >= 3) ? 2 : 0) + ((pass == 2 || pass == 5) ? 1 : 0);
        int bp = ((pass >= 3) ? 2 : 0) + ((pass == 1 || pass == 4) ? 1 : 0);
        const char* Zp = Zb + ((size_t)ap * 1024 + s0) * 384;
        const char* Bp = Bb + ((size_t)bp * TXD + t0) * 384;
        for (int k0 = 0; k0 < 384; k0 += 128) {
            __syncthreads();
#pragma unroll
            for (int j = 0; j < 8; ++j) {
                int c = w * 8 + j;
                glds16(Zp + (size_t)c * (8 * 384) + gOff + k0, As + c * 1024);
            }
#pragma unroll
            for (int j = 0; j < 4; ++j) {
                int c = w * 4 + j;
                glds16(Bp + (size_t)c * (8 * 384) + gOff + k0, Bs + c * 1024);
            }
            __syncthreads();
#pragma unroll
            for (int ks = 0; ks < 2; ++ks) {
                int so = ks ? slot1 : slot0;
                f16x8 av[4], bv[8];
#pragma unroll
                for (int fm = 0; fm < 4; ++fm)
                    av[fm] = *(const f16x8*)(As + arow_off + fm * (16 * 128) + so);
#pragma unroll
                for (int fn = 0; fn < 8; ++fn)
                    bv[fn] = *(const f16x8*)(Bs + brow_off + fn * (16 * 128) + so);
#pragma unroll
                for (int fm = 0; fm < 4; ++fm)
#pragma unroll
                    for (int fn = 0; fn < 8; ++fn)
                        acc[fm][fn] = __builtin_amdgcn_mfma_f32_16x16x32_f16(
                            av[fm], bv[fn], acc[fm][fn], 0, 0, 0);
            }
        }
    }
    float l14v[8];
#pragma unroll
    for (int fn = 0; fn < 8; ++fn) l14v[fn] = l14[b * TXD + t0 + fn * 16 + (l & 15)];
    int sb = sg0 + w * 64 + (l >> 4) * 4;
    int tcol = t0 + (l & 15);
#pragma unroll
    for (int fm = 0; fm < 4; ++fm)
#pragma unroll
        for (int r = 0; r < 4; ++r) {
            int sg = sb + fm * 16 + r;
            bool sv = sg < tyb;
            float* Lrow = L + ((size_t)b * TYD + sg) * TXD;
#pragma unroll
            for (int fn = 0; fn < 8; ++fn) {
                int t = tcol + fn * 16;
                Lrow[t] = (sv && t < txb) ? (acc[fm][fn][r] + l14v[fn]) : NEGV;
            }
        }
}

// ---------------- K3: Viterbi DP, producer/consumer + DPP wave_shr boundary ----------------
// Identical to the round-6 structure (producer wave + reg ping-pong consumer),
// EXCEPT the per-row __shfl_up (ds_bpermute, ~120cy LDS-pipe latency with a
// compiler lgkmcnt(0) at use) is replaced with v_mov_b32_dpp wave_shr:1 —
// a pure-VALU lane shift (~4-8cy, no lgkmcnt). Lane0 patched to NEGV as before;
// lane0's pp0_ is never consumed (NEGV > v[0] is always false).
__global__ __launch_bounds__(128) void k_dp(const float* __restrict__ L,
                                            const unsigned* __restrict__ txty,
                                            unsigned* __restrict__ dirsG,
                                            unsigned short* __restrict__ pathG,
                                            unsigned* __restrict__ ystartG,
                                            float* __restrict__ outDur) {
    __shared__ __align__(16) float ring[32 * 512];   // 64 KB
    __shared__ unsigned char dmaps[32 * 512];        // 16 KB
    __shared__ unsigned short path[TYD];             // 4 KB
    __shared__ unsigned cnt[513];
    __shared__ unsigned ebuf[32];
    int b = blockIdx.x, tid = threadIdx.x;
    int lane = tid & 63, wid = tid >> 6;
    int tx = (int)txty[b], ty = (int)txty[BB + b];
    const char* Lb = (const char*)(L + (size_t)b * (TYD * TXD));
    unsigned* dGw = dirsG + (size_t)b * (512 * 64);
    int G8 = (ty + 7) >> 3;

    if (wid == 1) {
        // ---------------- producer wave (unchanged) ----------------
        int c0s = lane ^ ((lane >> 3) & 7);
        int srcOff0 = c0s * 16;
        int srcOff1 = srcOff0 + 1024;
        char* ringc = (char*)ring;
#define STAGE_GRP(GR) do {                                                  \
        _Pragma("unroll")                                                   \
        for (int q_ = 0; q_ < 8; ++q_) {                                    \
            int r_ = 8 * (GR) + q_;                                         \
            int rc_ = min(r_, ty - 1);                                      \
            const char* src_ = Lb + (size_t)rc_ * 2048;                     \
            char* dst_ = ringc + (size_t)(r_ & 31) * 2048;                  \
            glds16(src_ + srcOff0, dst_);                                   \
            glds16(src_ + srcOff1, dst_ + 1024);                            \
        } } while (0)
        STAGE_GRP(0); STAGE_GRP(1); STAGE_GRP(2);          // 48 outstanding
        asm volatile("s_waitcnt vmcnt(16)" ::: "memory");  // groups 0,1 landed
        __builtin_amdgcn_s_barrier();                      // barrier #0
        for (int g = 0; g < G8; ++g) {
            __builtin_amdgcn_sched_barrier(0);
            STAGE_GRP(g + 3);                              // 32 outstanding
            asm volatile("s_waitcnt vmcnt(16)" ::: "memory"); // group g+2 landed
            __builtin_amdgcn_s_barrier();                  // barrier #(g+1)
        }
#undef STAGE_GRP
    } else {
        // ---------------- consumer wave (DP) ----------------
        int sl0 = (2 * lane) ^ ((lane >> 2) & 7);
        int sl1 = sl0 ^ 1;
        const char* ringc = (const char*)ring;
        float v[8];
        unsigned p[8];
        float4 loA[8], hiA[8], loB[8], hiB[8];
#define READ_GRP(LO, HI, GN) do {                                           \
        const char* rb_ = ringc + (((GN) & 3) << 14);                       \
        _Pragma("unroll")                                                   \
        for (int q_ = 0; q_ < 8; ++q_) {                                    \
            LO[q_] = *(const float4*)(rb_ + q_ * 2048 + sl0 * 16);          \
            HI[q_] = *(const float4*)(rb_ + q_ * 2048 + sl1 * 16);          \
        } } while (0)
#define DP_GRP(LO, HI, G_) do {                                             \
        unsigned w0_ = 0, w1_ = 0;                                          \
        _Pragma("unroll")                                                   \
        for (int q_ = 0; q_ < 8; ++q_) {                                    \
            int y_ = 8 * (G_) + q_;                                         \
            if ((G_) == 0 && q_ == 0) {                                     \
                float lp_[8] = {LO[0].x, LO[0].y, LO[0].z, LO[0].w,         \
                                HI[0].x, HI[0].y, HI[0].z, HI[0].w};        \
                _Pragma("unroll")                                           \
                for (int i = 0; i < 8; ++i) {                               \
                    int x_ = lane * 8 + i;                                  \
                    v[i] = (x_ == 0) ? lp_[i] : NEGV;                       \
                    p[i] = (unsigned)x_;                                    \
                }                                                           \
            } else if (y_ < ty) {                                           \
                float cur_[8] = {LO[q_].x, LO[q_].y, LO[q_].z, LO[q_].w,    \
                                 HI[q_].x, HI[q_].y, HI[q_].z, HI[q_].w};   \
                float vp0_ = __int_as_float(__builtin_amdgcn_mov_dpp(       \
                    __float_as_int(v[7]), 0x138, 0xf, 0xf, true));          \
                unsigned pp0_ = (unsigned)__builtin_amdgcn_mov_dpp(         \
                    (int)p[7], 0x138, 0xf, 0xf, true);                      \
                if (lane == 0) vp0_ = NEGV;                                 \
                unsigned bits_ = 0;                                         \
                _Pragma("unroll")                                           \
                for (int i = 7; i >= 0; --i) {                              \
                    float vp_ = (i == 0) ? vp0_ : v[i - 1];                 \
                    unsigned pp_ = (i == 0) ? pp0_ : p[i - 1];              \
                    bool d_ = vp_ > v[i];                                   \
                    v[i] = cur_[i] + (d_ ? vp_ : v[i]);                     \
                    p[i] = d_ ? pp_ : p[i];                                 \
                    bits_ |= (d_ ? 1u : 0u) << i;                           \
                }                                                           \
                if (q_ < 4) w0_ |= bits_ << (8 * q_);                       \
                else        w1_ |= bits_ << (8 * (q_ - 4));                 \
                if (q_ == 0 && ((G_) & 7) == 0 && (G_) != 0) {              \
                    _Pragma("unroll")                                       \
                    for (int i = 0; i < 8; ++i) p[i] = (unsigned)(lane * 8 + i); \
                }                                                           \
                if (q_ == 7 && ((G_) & 7) == 7) {                           \
                    int c_ = y_ >> 6;                                       \
                    _Pragma("unroll")                                       \
                    for (int i = 0; i < 8; ++i)                             \
                        dmaps[c_ * 512 + lane * 8 + i] =                    \
                            (unsigned char)((unsigned)(lane * 8 + i) - p[i]); \
                }                                                           \
            }                                                               \
        }                                                                   \
        dGw[(2 * (G_)) * 64 + lane] = w0_;                                  \
        dGw[(2 * (G_) + 1) * 64 + lane] = w1_;                              \
        } while (0)
        __builtin_amdgcn_s_barrier();                  // barrier #0
        __builtin_amdgcn_sched_barrier(0);
        READ_GRP(loA, hiA, 0);
        for (int g = 0; g < G8;) {
            READ_GRP(loB, hiB, g + 1);   // landed by barrier #g; hides under DP below
            DP_GRP(loA, hiA, g);
            ++g;
            __builtin_amdgcn_s_barrier();              // barrier #g
            __builtin_amdgcn_sched_barrier(0);
            if (g >= G8) break;
            READ_GRP(loA, hiA, g + 1);
            DP_GRP(loB, hiB, g);
            ++g;
            __builtin_amdgcn_s_barrier();              // barrier #g
            __builtin_amdgcn_sched_barrier(0);
        }
#undef READ_GRP
#undef DP_GRP
    }
    asm volatile("s_waitcnt vmcnt(0)" ::: "memory");  // consumer: dirs stores visible
    __syncthreads();

    int c0 = (ty - 1) >> 6;
    if (tid == 0) {
        int pos = tx - 1;
        for (int y = ty - 1; y >= (c0 << 6); --y) {  // top partial chunk
            path[y] = (unsigned short)pos;
            unsigned wv = dGw[(y >> 2) * 64 + (pos >> 3)];
            pos -= (int)((wv >> (((y & 3) << 3) | (pos & 7))) & 1u);
        }
        for (int c = c0 - 1; c >= 0; --c) {  // chunk-boundary resolution via dmaps
            ebuf[c] = (unsigned)pos;
            int P = pos - (int)dmaps[c * 512 + pos];
            unsigned wv = dGw[(c << 4) * 64 + (P >> 3)];  // row c*64 -> dword group c*16
            pos = P - (int)((wv >> (P & 7)) & 1u);
        }
    }
    __syncthreads();
    if (tid < c0) {  // parallel per-chunk chases (c0 <= 31 -> wave 0)
        int c = tid;
        int pos = (int)ebuf[c];
        for (int y = (c << 6) + 63; y >= (c << 6); --y) {
            path[y] = (unsigned short)pos;
            unsigned wv = dGw[(y >> 2) * 64 + (pos >> 3)];
            pos -= (int)((wv >> (((y & 3) << 3) | (pos & 7))) & 1u);
        }
    }
    __syncthreads();

    for (int i = tid; i < 513; i += 128) cnt[i] = 0;
    __syncthreads();
    for (int y = tid; y < ty; y += 128) atomicAdd(&cnt[path[y]], 1u);
    __syncthreads();

    if (wid == 0) {
        unsigned c8[8], lsum = 0;
#pragma unroll
        for (int i = 0; i < 8; ++i) {
            c8[i] = cnt[lane * 8 + i];
            lsum += c8[i];
        }
        unsigned incl = lsum;
        for (int d = 1; d < 64; d <<= 1) {
            unsigned t = (unsigned)__shfl_up((int)incl, d);
            if (lane >= d) incl += t;
        }
        unsigned run = incl - lsum;
#pragma unroll
        for (int i = 0; i < 8; ++i) {
            int x = lane * 8 + i;
            ystartG[b * 513 + x] = run;
            outDur[(size_t)b * TXD + x] = (float)c8[i];
            run += c8[i];
        }
        if (lane == 0) ystartG[b * 513 + 512] = (unsigned)ty;
    }
    for (int y = tid; y < ty; y += 128) pathG[b * TYD + y] = path[y];
}

// ---------------- K4: dense attn rows (f32 0/1) ----------------
__global__ __launch_bounds__(64) void k_attn(const unsigned* __restrict__ ystartG,
                                             float* __restrict__ out) {
    int x = blockIdx.x, b = blockIdx.y, lane = threadIdx.x;
    unsigned s0 = ystartG[b * 513 + x];
    unsigned s1 = ystartG[b * 513 + x + 1];
    float* row = out + E_ATTN + ((size_t)(b * TXD + x)) * TYD + lane * 32;
#pragma unroll
    for (int k = 0; k < 8; ++k) {
        unsigned y0 = (unsigned)(lane * 32 + k * 4);
        float4 o;
        o.x = (y0 + 0 >= s0 && y0 + 0 < s1) ? 1.0f : 0.0f;
        o.y = (y0 + 1 >= s0 && y0 + 1 < s1) ? 1.0f : 0.0f;
        o.z = (y0 + 2 >= s0 && y0 + 2 < s1) ? 1.0f : 0.0f;
        o.w = (y0 + 3 >= s0 && y0 + 3 < s1) ? 1.0f : 0.0f;
        *(float4*)(row + k * 4) = o;
    }
}

// ---------------- K5: m_p_dur / logs_p_dur gathers (f32) ----------------
__global__ __launch_bounds__(256) void k_gather(const float* __restrict__ m_p,
                                                const float* __restrict__ logs_p,
                                                const unsigned short* __restrict__ pathG,
                                                const unsigned* __restrict__ txty,
                                                float* __restrict__ out) {
    __shared__ unsigned short px[64];
    int yc = blockIdx.x, b = blockIdx.y;
    int y0 = yc * 64, tid = threadIdx.x;
    int lane = tid & 63, w = tid >> 6;
    int ty = (int)txty[BB + b];
    if (tid < 64) px[tid] = (y0 + tid < ty) ? pathG[b * TYD + y0 + tid] : 0;
    __syncthreads();
    bool act = (y0 + lane) < ty;
    int xx = (int)px[lane];
    for (int c = w; c < CC; c += 4) {
        float mv = act ? m_p[((size_t)b * CC + c) * TXD + xx] : 0.0f;
        float lv = act ? logs_p[((size_t)b * CC + c) * TXD + xx] : 0.0f;
        size_t oidx = ((size_t)(b * CC + c)) * TYD + y0 + lane;
        out[E_MP + oidx] = mv;
        out[E_LS + oidx] = lv;
    }
}

extern "C" void kernel_launch(void* const* d_in, const int* in_sizes, int n_in,
                              void* d_out, int out_size, void* d_ws, size_t ws_size,
                              hipStream_t stream) {
    if (out_size < E_TOTAL) return;
    if (ws_size < WS_NEED) return;
    const float* z_p    = (const float*)d_in[0];
    const float* m_p    = (const float*)d_in[1];
    const float* logs_p = (const float*)d_in[2];
    const int* xl       = (const int*)d_in[3];
    const int* yl       = (const int*)d_in[4];
    float* out = (float*)d_out;
    char* ws = (char*)d_ws;

    float* l14            = out + E_DUR;
    float* L              = out + E_ATTN;
    _Float16* Zpl         = (_Float16*)(out + E_MP);
    _Float16* Bpl         = (_Float16*)(out + E_LS);
    unsigned* dirsG       = (unsigned*)(out + E_LS + OFF_DIRS);
    unsigned short* pathG = (unsigned short*)(ws + WS_PATH);
    unsigned* ystartG     = (unsigned*)(ws + WS_YST);
    unsigned* txty        = (unsigned*)(ws + WS_TXTY);

    hipLaunchKernelGGL(k_prepB, dim3(16, BB), dim3(256), 0, stream,
                       logs_p, m_p, xl, yl, Bpl, l14, txty);
    hipLaunchKernelGGL(k_prepZ, dim3(16, BB), dim3(256), 0, stream, z_p, Zpl, 0);
    hipLaunchKernelGGL(k_mm, dim3(512), dim3(256), 0, stream, Zpl, Bpl, l14, txty, L, 0);
    hipLaunchKernelGGL(k_prepZ, dim3(16, BB), dim3(256), 0, stream, z_p, Zpl, 1024);
    hipLaunchKernelGGL(k_mm, dim3(512), dim3(256), 0, stream, Zpl, Bpl, l14, txty, L, 1024);
    hipLaunchKernelGGL(k_dp, dim3(BB), dim3(128), 0, stream, L, txty, dirsG, pathG, ystartG, out + E_DUR);
    hipLaunchKernelGGL(k_attn, dim3(TXD, BB), dim3(64), 0, stream, ystartG, out);
    hipLaunchKernelGGL(k_gather, dim3(TYD / 64, BB), dim3(256), 0, stream, m_p, logs_p, pathG, txty, out);
}